// Round 7
// baseline (252.438 us; speedup 1.0000x reference)
//
#include <hip/hip_runtime.h>

#define SEQ    2048
#define BATCH  2
#define NHQ    32
#define NHKV   8
#define DHEAD  128
// 1/sqrt(128) * log2(e): QK^T logits produced directly in log2 domain,
// so softmax uses raw v_exp_f32 (exp2) with no per-score multiply.
#define QSCALE2 0.12751743f

typedef __fp16 f16;
typedef f16 f16x2 __attribute__((ext_vector_type(2)));
typedef f16 f16x4 __attribute__((ext_vector_type(4)));
typedef f16 f16x8 __attribute__((ext_vector_type(8)));
typedef float f32x4 __attribute__((ext_vector_type(4)));

#define KSTRIDE 136                 // halfs per K row (128 + 8 pad)
#define VSTRIDE 72                  // halfs per Vt row (64 k + 8 pad; 144B rows, 16B-aligned)
#define KBUF    (64 * KSTRIDE)      // 8704 halfs  (BK=64 staged tile)
#define VBUF    (128 * VSTRIDE)     // 9216 halfs

static __device__ __forceinline__ float fast_exp2(float x) {
#if __has_builtin(__builtin_amdgcn_exp2f)
  return __builtin_amdgcn_exp2f(x);
#else
  return __builtin_exp2f(x);
#endif
}

// v7 = v6 + BK=64 double-subtile staging (half the barriers, half the
// staging-loop overhead, 2x prefetch latency coverage) + softmax VALU trim
// (v_max3-fusable max tree; row-sum via v_dot2_f32_f16 on the packed f16
// pairs -> denominator numerically consistent with the f16 P used in PV).
// LDS 71,680 B -> still 2 blocks/CU (unchanged residency); compute stays at
// 32-k sub-tile granularity (all verified bank patterns preserved).
// v6 history: XCD-locality swizzle (FETCH 175->56 MB), setprio on MFMA
// clusters, lane-local l defer. v5: PV as one 16x16x32 per d-block via
// write-side K-row permutation inv(k); exp2-domain softmax. v4: uniform-
// cost q-tile pairs {15-i,i}; 8-wave staging; conflict-free V column
// staging; direct epilogue; defer-max. 144.5 us at round 6.
__global__ __launch_bounds__(512, 4) void attn_fwd(const float* __restrict__ Q,
                                                   const float* __restrict__ K,
                                                   const float* __restrict__ V,
                                                   float* __restrict__ O) {
  // XCD-locality swizzle (perf heuristic only; any mapping is correct)
  const int bh     = (int)blockIdx.x * 8 + ((int)blockIdx.y >> 3);
  const int pair_i = (int)blockIdx.y & 7;
  const int b   = bh >> 5;
  const int hq  = bh & 31;
  const int hkv = hq >> 2;
  const int t    = threadIdx.x;
  const int wave = t >> 6;
  const int lane = t & 63;
  const int col  = lane & 15;
  const int quad = lane >> 4;

  const int qrs = BATCH * NHQ * DHEAD;    // 8192
  const int krs = BATCH * NHKV * DHEAD;   // 2048

  const float* Qp = Q + ((size_t)b * NHQ  + hq ) * DHEAD;
  const float* Kp = K + ((size_t)b * NHKV + hkv) * DHEAD;
  const float* Vp = V + ((size_t)b * NHKV + hkv) * DHEAD;
  float*       Op = O + ((size_t)b * NHQ  + hq ) * DHEAD;

  __shared__ __align__(16) f16 smem[2 * KBUF + 2 * VBUF];  // 71680 B

  // staging coords (BK=64): K rows via float4 (4 rows/thread),
  // V via d-columns (lane=d, two k-octets) -> contiguous f16x8 writes
  const int ktk = t >> 5;            // base kv row 0..15 (+16*ro)
  const int ktd = (t & 31) * 4;
  const int vd  = t & 127;           // Vt row (d)
  const int vh  = t >> 7;            // 0..3 -> k-octet within each 32-half
  // permuted LDS row for K staging (per 32-k sub-tile):
  // inv(k) = ((k>>2)&1)*16 + (k>>3)*4 + (k&3); inv(k+16) = inv(k)+8.
  const int klr = ((ktk >> 2) & 1) * 16 + (ktk >> 3) * 4 + (ktk & 3);

  const f16x2 kOne = {(f16)1.f, (f16)1.f};

  #pragma unroll 1
  for (int pass = 0; pass < 2; ++pass) {
    // heavy tile first; pair sums to 15 -> all blocks cost 34 staged tiles
    const int qt     = pass ? pair_i : 15 - pair_i;
    const int q_base = qt * 128 + wave * 16;

    // ---- Q fragments (B-operand of 16x16x32: B[n=col][k=quad*8+j]),
    //      pre-scaled by 1/sqrt(D)*log2(e) ----
    f16x8 qf[4];
    {
      const float* qsrc = Qp + (size_t)(q_base + col) * qrs + quad * 8;
      #pragma unroll
      for (int c = 0; c < 4; ++c) {
        float4 a = *(const float4*)(qsrc + c * 32);
        float4 e = *(const float4*)(qsrc + c * 32 + 4);
        f16x2 p0 = __builtin_amdgcn_cvt_pkrtz(a.x * QSCALE2, a.y * QSCALE2);
        f16x2 p1 = __builtin_amdgcn_cvt_pkrtz(a.z * QSCALE2, a.w * QSCALE2);
        f16x2 p2 = __builtin_amdgcn_cvt_pkrtz(e.x * QSCALE2, e.y * QSCALE2);
        f16x2 p3 = __builtin_amdgcn_cvt_pkrtz(e.z * QSCALE2, e.w * QSCALE2);
        qf[c][0] = p0[0]; qf[c][1] = p0[1]; qf[c][2] = p1[0]; qf[c][3] = p1[1];
        qf[c][4] = p2[0]; qf[c][5] = p2[1]; qf[c][6] = p3[0]; qf[c][7] = p3[1];
      }
    }

    f32x4 oacc[8];
    #pragma unroll
    for (int h = 0; h < 8; ++h) oacc[h] = (f32x4){0.f, 0.f, 0.f, 0.f};
    float m_i = -__builtin_inff();
    float l_i = 0.f;                  // lane-local partial (reduced in epilogue)

    const int nt2  = 2 * qt + 2;                  // staged (64-k) tiles, uniform
    const int nt_w = 4 * qt + (wave >> 1) + 1;    // causal 32-k sub-tiles

    float4 kr[4];
    float  vf[16];

    // prologue: global loads for staged tile 0 (64 kv rows)
    #pragma unroll
    for (int ro = 0; ro < 4; ++ro)
      kr[ro] = *(const float4*)(Kp + (size_t)(ktk + ro * 16) * krs + ktd);
    #pragma unroll
    for (int i = 0; i < 8; ++i) {
      vf[i]     = Vp[(size_t)(vh * 8 + i) * krs + vd];
      vf[8 + i] = Vp[(size_t)(vh * 8 + i + 32) * krs + vd];
    }

    for (int kt2 = 0; kt2 < nt2; ++kt2) {
      const int bf = kt2 & 1;
      f16* kb = smem + bf * KBUF;
      f16* vb = smem + 2 * KBUF + bf * VBUF;

      // ---- stage 64-k tile from registers (cvt + vectorized LDS writes) ----
      #pragma unroll
      for (int ro = 0; ro < 4; ++ro) {
        f16x2 lo = __builtin_amdgcn_cvt_pkrtz(kr[ro].x, kr[ro].y);
        f16x2 hi = __builtin_amdgcn_cvt_pkrtz(kr[ro].z, kr[ro].w);
        f16x4 v4; v4[0] = lo[0]; v4[1] = lo[1]; v4[2] = hi[0]; v4[3] = hi[1];
        // row ktk+16*ro -> LDS row (ro>>1)*32 + klr + (ro&1)*8  (permuted)
        *(f16x4*)(kb + ((ro >> 1) * 32 + klr + (ro & 1) * 8) * KSTRIDE + ktd) = v4;
      }
      #pragma unroll
      for (int g = 0; g < 2; ++g) {
        f16x2 p0 = __builtin_amdgcn_cvt_pkrtz(vf[g * 8 + 0], vf[g * 8 + 1]);
        f16x2 p1 = __builtin_amdgcn_cvt_pkrtz(vf[g * 8 + 2], vf[g * 8 + 3]);
        f16x2 p2 = __builtin_amdgcn_cvt_pkrtz(vf[g * 8 + 4], vf[g * 8 + 5]);
        f16x2 p3 = __builtin_amdgcn_cvt_pkrtz(vf[g * 8 + 6], vf[g * 8 + 7]);
        f16x8 v8;
        v8[0] = p0[0]; v8[1] = p0[1]; v8[2] = p1[0]; v8[3] = p1[1];
        v8[4] = p2[0]; v8[5] = p2[1]; v8[6] = p3[0]; v8[7] = p3[1];
        *(f16x8*)(vb + vd * VSTRIDE + g * 32 + vh * 8) = v8;  // 16B aligned
      }

      // ---- issue next staged tile's global loads (2 sub-tiles of cover) ----
      if (kt2 + 1 < nt2) {
        const int k0n = (kt2 + 1) * 64;
        #pragma unroll
        for (int ro = 0; ro < 4; ++ro)
          kr[ro] = *(const float4*)(Kp + (size_t)(k0n + ktk + ro * 16) * krs + ktd);
        #pragma unroll
        for (int i = 0; i < 8; ++i) {
          vf[i]     = Vp[(size_t)(k0n + vh * 8 + i) * krs + vd];
          vf[8 + i] = Vp[(size_t)(k0n + vh * 8 + i + 32) * krs + vd];
        }
      }

      __syncthreads();

      #pragma unroll
      for (int s = 0; s < 2; ++s) {
        const int sub = kt2 * 2 + s;
        if (sub < nt_w) {
          const int k0 = sub * 32;
          const f16* kbs = kb + (s * 32) * KSTRIDE;

          // ---- S^T = K Q^T (permuted staging => lane-local k-order
          //      quad*8+r / quad*8+4+r) ----
          f32x4 s0 = {0.f, 0.f, 0.f, 0.f}, s1 = {0.f, 0.f, 0.f, 0.f};
          __builtin_amdgcn_s_setprio(1);
          #pragma unroll
          for (int c = 0; c < 4; ++c) {
            f16x8 ka = *(const f16x8*)(kbs + col * KSTRIDE + quad * 8 + c * 32);
            s0 = __builtin_amdgcn_mfma_f32_16x16x32_f16(ka, qf[c], s0, 0, 0, 0);
          }
          #pragma unroll
          for (int c = 0; c < 4; ++c) {
            f16x8 ka = *(const f16x8*)(kbs + (16 + col) * KSTRIDE + quad * 8 + c * 32);
            s1 = __builtin_amdgcn_mfma_f32_16x16x32_f16(ka, qf[c], s1, 0, 0, 0);
          }
          __builtin_amdgcn_s_setprio(0);

          // ---- causal mask; q = col, s0[r] -> k = quad*8+r, s1[r] -> +4 ----
          const int qrow = q_base + col;
          if (k0 + 31 > q_base) {
            #pragma unroll
            for (int r = 0; r < 4; ++r) {
              if (k0 + quad * 8 + r     > qrow) s0[r] = -__builtin_inff();
              if (k0 + quad * 8 + 4 + r > qrow) s1[r] = -__builtin_inff();
            }
          }

          // ---- online softmax, log2 domain, defer-max (P <= 2^8) ----
          // max tree in v_max3-fusable shape: 4 instrs
          float m1 = fmaxf(fmaxf(s0[0], s0[1]), s0[2]);
          float m2 = fmaxf(fmaxf(s0[3], s1[0]), s1[1]);
          float m3 = fmaxf(fmaxf(s1[2], s1[3]), m1);
          float mx = fmaxf(m2, m3);
          mx = fmaxf(mx, __shfl_xor(mx, 16, 64));
          mx = fmaxf(mx, __shfl_xor(mx, 32, 64));

          if (!__all(mx - m_i <= 8.0f)) {   // first tile: +inf -> rescale path
            const float mnew  = fmaxf(m_i, mx);
            const float alpha = fast_exp2(m_i - mnew);   // first tile: 0
            m_i = mnew;
            l_i *= alpha;
            #pragma unroll
            for (int h = 0; h < 8; ++h) {
              oacc[h][0] *= alpha; oacc[h][1] *= alpha;
              oacc[h][2] *= alpha; oacc[h][3] *= alpha;
            }
          }

          float e0[4], e1[4];
          #pragma unroll
          for (int r = 0; r < 4; ++r) {
            e0[r] = fast_exp2(s0[r] - m_i);
            e1[r] = fast_exp2(s1[r] - m_i);
          }

          // ---- P^T pack: f16x8 B-operand, k = quad*8 + j ----
          f16x2 a01 = __builtin_amdgcn_cvt_pkrtz(e0[0], e0[1]);
          f16x2 a23 = __builtin_amdgcn_cvt_pkrtz(e0[2], e0[3]);
          f16x2 b01 = __builtin_amdgcn_cvt_pkrtz(e1[0], e1[1]);
          f16x2 b23 = __builtin_amdgcn_cvt_pkrtz(e1[2], e1[3]);
          f16x8 pb;
          pb[0] = a01[0]; pb[1] = a01[1]; pb[2] = a23[0]; pb[3] = a23[1];
          pb[4] = b01[0]; pb[5] = b01[1]; pb[6] = b23[0]; pb[7] = b23[1];

          // row-sum of P in f16 pairs (consistent with PV numerator)
#if __has_builtin(__builtin_amdgcn_fdot2)
          float rs = __builtin_amdgcn_fdot2(a01, kOne,
                       __builtin_amdgcn_fdot2(a23, kOne,
                         __builtin_amdgcn_fdot2(b01, kOne,
                           __builtin_amdgcn_fdot2(b23, kOne, 0.f, false),
                           false), false), false);
#else
          float rs = 0.f;
          #pragma unroll
          for (int r = 0; r < 4; ++r) rs += e0[r] + e1[r];
#endif
          l_i += rs;                  // lane-local; cross-quad reduce deferred

          // ---- O^T += V^T P^T : one 16x16x32 per 16-d block ----
          __builtin_amdgcn_s_setprio(1);
          #pragma unroll
          for (int h = 0; h < 8; ++h) {
            f16x8 va = *(const f16x8*)(vb + (h * 16 + col) * VSTRIDE + s * 32 + quad * 8);
            oacc[h] = __builtin_amdgcn_mfma_f32_16x16x32_f16(va, pb, oacc[h], 0, 0, 0);
          }
          __builtin_amdgcn_s_setprio(0);
        }
      }
    }

    // ---- epilogue: reduce l across quads once, direct stores ----
    {
      float lt = l_i + __shfl_xor(l_i, 16, 64);
      lt += __shfl_xor(lt, 32, 64);
      const float invl = 1.0f / lt;
      #pragma unroll
      for (int h = 0; h < 8; ++h) {
        float4 o;
        o.x = oacc[h][0] * invl; o.y = oacc[h][1] * invl;
        o.z = oacc[h][2] * invl; o.w = oacc[h][3] * invl;
        *(float4*)(Op + (size_t)(q_base + col) * qrs + h * 16 + quad * 4) = o;
      }
    }
  }
}

extern "C" void kernel_launch(void* const* d_in, const int* in_sizes, int n_in,
                              void* d_out, int out_size, void* d_ws, size_t ws_size,
                              hipStream_t stream) {
  const float* Q = (const float*)d_in[0];
  const float* K = (const float*)d_in[1];
  const float* V = (const float*)d_in[2];
  float* O = (float*)d_out;
  (void)in_sizes; (void)n_in; (void)out_size; (void)d_ws; (void)ws_size;
  dim3 grid(SEQ / 256, BATCH * NHQ);   // swizzled: bh = x*8 + (y>>3), i = y&7
  attn_fwd<<<grid, dim3(512), 0, stream>>>(Q, K, V, O);
}